// Round 10
// baseline (109.710 us; speedup 1.0000x reference)
//
#include <hip/hip_runtime.h>
#include <hip/hip_fp16.h>
#include <cstdint>
#include <cstddef>

// ---- problem constants ----
#define SEQ 2048
#define DM 1024
#define NH 16
#define NB 20

typedef _Float16 half8 __attribute__((ext_vector_type(8)));
typedef _Float16 half4 __attribute__((ext_vector_type(4)));
typedef _Float16 h2v __attribute__((ext_vector_type(2)));
typedef float f32x4 __attribute__((ext_vector_type(4)));
typedef int i32x4 __attribute__((ext_vector_type(4)));
typedef unsigned int u32;
typedef unsigned int u32x2 __attribute__((ext_vector_type(2)));

// ws layout (25,165,824 B total):
//  KF [2][16][64][2048] halves : per (b,h,kt): [k2][dh][lane][8]   (QK^T A-frags)
//  VF [2][16][64][2048] halves : per (b,h,kt): [k2][dtp][lane][8]  (PV B-frags)
//  PB [2][64][65536] bytes     : per (b,qblk32): [kt][lane][qs][k2][4] bucket*4|sentinel80
#define KF_HALVES 4194304
#define VF_HALVES 4194304

// =================== prepass: fragment-order everything (unchanged) ===================
__global__ __launch_bounds__(256) void pa_prep(
    const float* __restrict__ v, const float* __restrict__ k,
    const int* __restrict__ diff, const int* __restrict__ mask,
    _Float16* __restrict__ KF, _Float16* __restrict__ VF,
    unsigned char* __restrict__ PB) {
  const int bid = blockIdx.x, tid = threadIdx.x;
  if (bid < 2048) {
    int img = bid >> 4;                    // 0..127 = b*64+kt
    int bb = img >> 6, kt = img & 63;
    int tix = ((bid & 15) << 8) | tid;     // 0..4095
    int r = tix >> 7;                      // row in tile 0..31 (= k2*16+l16)
    int c0 = (tix & 127) << 3;             // col 0..1016
    const float* src = k + ((size_t)(bb * SEQ + kt * 32 + r)) * DM + c0;
    f32x4 a = *(const f32x4*)src;
    f32x4 c = *(const f32x4*)(src + 4);
    half8 o = {(_Float16)a[0], (_Float16)a[1], (_Float16)a[2], (_Float16)a[3],
               (_Float16)c[0], (_Float16)c[1], (_Float16)c[2], (_Float16)c[3]};
    int h = c0 >> 6, dh = (c0 >> 5) & 1, g4 = (c0 >> 3) & 3;
    int k2 = r >> 4, l16 = r & 15;
    int lane = g4 * 16 + l16;
    size_t off = ((size_t)((bb * 16 + h) * 64 + kt)) * 2048 + (k2 * 2 + dh) * 512 + lane * 8;
    *(half8*)(KF + off) = o;
  } else if (bid < 3072) {
    int b3 = bid - 2048;
    int img = b3 >> 3;                     // 0..127
    int bb = img >> 6, kt = img & 63;
    int tix = ((b3 & 7) << 8) | tid;       // 0..2047
    int kq = tix >> 8;                     // 0..7
    int k2 = kq >> 2, g4 = kq & 3;
    int d0 = (tix & 255) << 2;             // 0..1020
    const float* src = v + ((size_t)(bb * SEQ + kt * 32 + k2 * 16 + g4 * 4)) * DM + d0;
    f32x4 m0 = *(const f32x4*)(src);
    f32x4 m1 = *(const f32x4*)(src + DM);
    f32x4 m2 = *(const f32x4*)(src + 2 * DM);
    f32x4 m3 = *(const f32x4*)(src + 3 * DM);
#pragma unroll
    for (int i = 0; i < 4; ++i) {
      int d = d0 + i;
      int l16 = d & 15, dt = (d >> 4) & 3, dtp = dt >> 1, w = dt & 1, h = d >> 6;
      int lane = g4 * 16 + l16;
      half4 o = {(_Float16)m0[i], (_Float16)m1[i], (_Float16)m2[i], (_Float16)m3[i]};
      size_t off = ((size_t)((bb * 16 + h) * 64 + kt)) * 2048 + (k2 * 2 + dtp) * 512 + lane * 8 + w * 4;
      *(half4*)(VF + off) = o;
    }
  } else {
    int b4 = bid - 3072;                   // 0..4095
    int job = b4 >> 5;                     // 0..127 = b*64+qblk
    int bb = job >> 6, qblk = job & 63;
    int tix = ((b4 & 31) << 8) | tid;      // 0..8191
    int kt = tix >> 7;
    int rem = tix & 127;
    int g4 = rem & 3, l16 = (rem >> 2) & 15, qs = rem >> 6;
    int lane = g4 * 16 + l16;
    int qrow = qblk * 32 + qs * 16 + l16;
    size_t rowbase = ((size_t)(bb * SEQ + qrow)) * SEQ;
    u32x2 wds;
#pragma unroll
    for (int k2 = 0; k2 < 2; ++k2) {
      int kk = kt * 32 + k2 * 16 + g4 * 4;
      i32x4 dv = *(const i32x4*)(diff + rowbase + kk);
      i32x4 mv = *(const i32x4*)(mask + rowbase + kk);
      u32 wd = 0;
#pragma unroll
      for (int r = 0; r < 4; ++r) {
        u32 byte = mv[r] ? ((u32)dv[r] << 2) : 80u;  // bucket*4; 80 = masked sentinel lane 20
        wd |= byte << (8 * r);
      }
      wds[k2] = wd;
    }
    size_t off = ((size_t)job) * 65536 + (size_t)kt * 1024 + (size_t)lane * 16 + (size_t)qs * 8;
    *(u32x2*)(PB + off) = wds;
  }
}

__device__ __forceinline__ void gll16(const _Float16* g, _Float16* l) {
  __builtin_amdgcn_global_load_lds(
      (const __attribute__((address_space(1))) unsigned int*)g,
      (__attribute__((address_space(3))) unsigned int*)l, 16, 0, 0);
}

// packed-f16 silu with pre-gathered f16 bias pairs
__device__ __forceinline__ half4 silu4b(const f32x4& s, h2v b01, h2v b23) {
  h2v x01 = __builtin_bit_cast(h2v, __builtin_amdgcn_cvt_pkrtz(s[0], s[1])) + b01;
  h2v x23 = __builtin_bit_cast(h2v, __builtin_amdgcn_cvt_pkrtz(s[2], s[3])) + b23;
  const h2v NL2E = {(_Float16)-1.44269504f, (_Float16)-1.44269504f};
  const h2v ONE = {(_Float16)1.0f, (_Float16)1.0f};
  h2v m01 = x01 * NL2E, m23 = x23 * NL2E;
  h2v e01 = __builtin_bit_cast(h2v, h2exp2(__builtin_bit_cast(__half2, m01)));
  h2v e23 = __builtin_bit_cast(h2v, h2exp2(__builtin_bit_cast(__half2, m23)));
  h2v d01 = e01 + ONE, d23 = e23 + ONE;
  h2v y01 = x01 * __builtin_bit_cast(h2v, h2rcp(__builtin_bit_cast(__half2, d01)));
  h2v y23 = x23 * __builtin_bit_cast(h2v, h2rcp(__builtin_bit_cast(__half2, d23)));
  return (half4){y01[0], y01[1], y23[0], y23[1]};
}

struct BiasSet { h2v b[2][2][2]; };  // [qs][k2][pair]

__device__ __forceinline__ void gather_bias(BiasSet& bs, const i32x4& pq, int rbi) {
#pragma unroll
  for (int qs = 0; qs < 2; ++qs)
#pragma unroll
    for (int k2 = 0; k2 < 2; ++k2) {
      u32 u = (u32)pq[qs * 2 + k2];
      float b0 = __int_as_float(__builtin_amdgcn_ds_bpermute((int)(u & 0xffu), rbi));
      float b1 = __int_as_float(__builtin_amdgcn_ds_bpermute((int)((u >> 8) & 0xffu), rbi));
      float b2 = __int_as_float(__builtin_amdgcn_ds_bpermute((int)((u >> 16) & 0xffu), rbi));
      float b3 = __int_as_float(__builtin_amdgcn_ds_bpermute((int)(u >> 24), rbi));
      bs.b[qs][k2][0] = __builtin_bit_cast(h2v, __builtin_amdgcn_cvt_pkrtz(b0, b1));
      bs.b[qs][k2][1] = __builtin_bit_cast(h2v, __builtin_amdgcn_cvt_pkrtz(b2, b3));
    }
}

// =================== main: block-shared LDS K/V staging ===================
// Theory: per-wave K/V register loads oversubscribe the per-CU L1 return path (64 B/cy)
// ~4.8x — the 4 waves of a block read IDENTICAL K/V (same head), so stage once per block
// into LDS via global_load_lds (KF/VF fragment-linear => wave-uniform dest works) and
// read via the separate 128 B/cy LDS pipe. Double-buffered, 1 barrier/iter.
__global__ __launch_bounds__(256, 4) void pa_main(
    const _Float16* __restrict__ KF, const _Float16* __restrict__ VF,
    const unsigned char* __restrict__ PB, const float* __restrict__ q,
    const float* __restrict__ relbias, float* __restrict__ out) {
  __shared__ _Float16 ldsK[2][2048];
  __shared__ _Float16 ldsV[2][2048];

  const int tid = threadIdx.x, lane = tid & 63, wid = tid >> 6;
  const int l16 = lane & 15, g4 = lane >> 4;
  const int L = (blockIdx.x & 7) * 128 + (blockIdx.x >> 3);   // bijective, 8 XCDs x 128
  const int h = L & 15;
  const int qgrp = (L >> 4) & 15;
  const int ksp = (L >> 8) & 1;
  const int b = L >> 9;
  const int qblk = qgrp * 4 + wid;
  const int qbase = qblk * 32;

  const float rbv = (lane < NB) ? relbias[lane * NH + h] : -30000.0f;
  const int rbi = __float_as_int(rbv);

  half8 qf[2][2];
#pragma unroll
  for (int qs = 0; qs < 2; ++qs)
#pragma unroll
    for (int dh = 0; dh < 2; ++dh) {
      const float* s = q + ((size_t)(b * SEQ + qbase + qs * 16 + l16)) * DM + h * 64 + dh * 32 + g4 * 8;
      f32x4 a = *(const f32x4*)s;
      f32x4 c = *(const f32x4*)(s + 4);
      qf[qs][dh] = {(_Float16)(a[0] * 0.125f), (_Float16)(a[1] * 0.125f),
                    (_Float16)(a[2] * 0.125f), (_Float16)(a[3] * 0.125f),
                    (_Float16)(c[0] * 0.125f), (_Float16)(c[1] * 0.125f),
                    (_Float16)(c[2] * 0.125f), (_Float16)(c[3] * 0.125f)};
    }

  f32x4 acc[2][4];
#pragma unroll
  for (int qs = 0; qs < 2; ++qs)
#pragma unroll
    for (int dt = 0; dt < 4; ++dt) acc[qs][dt] = (f32x4){0.f, 0.f, 0.f, 0.f};

  // stage source: per-lane global addr (lane*8 halves); LDS dest: wave-uniform chunk base
  const _Float16* kfb = KF + ((size_t)((b * 16 + h) * 64 + ksp * 32)) * 2048 + lane * 8;
  const _Float16* vfb = VF + ((size_t)((b * 16 + h) * 64 + ksp * 32)) * 2048 + lane * 8;
  const unsigned char* pbb = PB + ((size_t)(b * 64 + qblk)) * 65536 + (size_t)(ksp * 32) * 1024 + lane * 16;
  const int c512 = wid * 512;

#define STAGE(T, B)                                          \
  do {                                                       \
    gll16(kfb + (size_t)(T) * 2048 + c512, &ldsK[B][c512]);  \
    gll16(vfb + (size_t)(T) * 2048 + c512, &ldsV[B][c512]);  \
  } while (0)
#define CLMP(T) ((T) < 32 ? (T) : 31)

#define COMPUTE(B, BS)                                                                       \
  do {                                                                                       \
    const f32x4 zf = {0.f, 0.f, 0.f, 0.f};                                                   \
    half8 kfr[4], vvr[4];                                                                    \
    _Pragma("unroll") for (int j = 0; j < 4; ++j) {                                          \
      kfr[j] = *(const half8*)&ldsK[B][j * 512 + lane * 8];                                  \
      vvr[j] = *(const half8*)&ldsV[B][j * 512 + lane * 8];                                  \
    }                                                                                        \
    _Pragma("unroll") for (int k2 = 0; k2 < 2; ++k2) {                                       \
      f32x4 sa[2];                                                                           \
      _Pragma("unroll") for (int qs = 0; qs < 2; ++qs) {                                     \
        sa[qs] = __builtin_amdgcn_mfma_f32_16x16x32_f16(kfr[k2 * 2 + 0], qf[qs][0], zf, 0, 0, 0); \
        sa[qs] = __builtin_amdgcn_mfma_f32_16x16x32_f16(kfr[k2 * 2 + 1], qf[qs][1], sa[qs], 0, 0, 0); \
      }                                                                                      \
      half4 pf[2];                                                                           \
      pf[0] = silu4b(sa[0], BS.b[0][k2][0], BS.b[0][k2][1]);                                 \
      pf[1] = silu4b(sa[1], BS.b[1][k2][0], BS.b[1][k2][1]);                                 \
      half4 vf0 = __builtin_shufflevector(vvr[k2 * 2 + 0], vvr[k2 * 2 + 0], 0, 1, 2, 3);     \
      half4 vf1 = __builtin_shufflevector(vvr[k2 * 2 + 0], vvr[k2 * 2 + 0], 4, 5, 6, 7);     \
      half4 vf2 = __builtin_shufflevector(vvr[k2 * 2 + 1], vvr[k2 * 2 + 1], 0, 1, 2, 3);     \
      half4 vf3 = __builtin_shufflevector(vvr[k2 * 2 + 1], vvr[k2 * 2 + 1], 4, 5, 6, 7);     \
      _Pragma("unroll") for (int qs = 0; qs < 2; ++qs) {                                     \
        acc[qs][0] = __builtin_amdgcn_mfma_f32_16x16x16f16(pf[qs], vf0, acc[qs][0], 0, 0, 0); \
        acc[qs][1] = __builtin_amdgcn_mfma_f32_16x16x16f16(pf[qs], vf1, acc[qs][1], 0, 0, 0); \
        acc[qs][2] = __builtin_amdgcn_mfma_f32_16x16x16f16(pf[qs], vf2, acc[qs][2], 0, 0, 0); \
        acc[qs][3] = __builtin_amdgcn_mfma_f32_16x16x16f16(pf[qs], vf3, acc[qs][3], 0, 0, 0); \
      }                                                                                      \
    }                                                                                        \
  } while (0)

  BiasSet biasA, biasB;
  i32x4 pq1, pqX;

  // prologue: stage tile0 -> buf0; bias(0); pq(1) in flight
  STAGE(0, 0);
  i32x4 pq0 = *(const i32x4*)(pbb);
  pq1 = *(const i32x4*)(pbb + 1024);
  __syncthreads();                      // drains stage(0)
  gather_bias(biasA, pq0, rbi);

  for (int t = 0; t < 32; t += 2) {
    // even phase: stage t+1 -> buf1; compute t from buf0
    STAGE(t + 1, 1);
    pqX = *(const i32x4*)(pbb + (size_t)CLMP(t + 2) * 1024);
    __builtin_amdgcn_sched_barrier(0);
    gather_bias(biasB, pq1, rbi);       // bias for t+1, hides under compute t
    COMPUTE(0, biasA);
    __syncthreads();                    // buf1 ready; all waves done with buf0
    // odd phase: stage t+2 -> buf0; compute t+1 from buf1
    STAGE(CLMP(t + 2), 0);
    pq1 = *(const i32x4*)(pbb + (size_t)CLMP(t + 3) * 1024);
    __builtin_amdgcn_sched_barrier(0);
    gather_bias(biasA, pqX, rbi);       // bias for t+2
    COMPUTE(1, biasB);
    __syncthreads();
  }
#undef STAGE
#undef CLMP
#undef COMPUTE

  // epilogue: ksplit=2 partials -> atomicAdd into zeroed out
#pragma unroll
  for (int qs = 0; qs < 2; ++qs)
#pragma unroll
    for (int dt = 0; dt < 4; ++dt)
#pragma unroll
      for (int r = 0; r < 4; ++r) {
        int qrow = qbase + qs * 16 + g4 * 4 + r;
        int d = h * 64 + dt * 16 + l16;
        atomicAdd(&out[((size_t)(b * SEQ) + qrow) * DM + d], acc[qs][dt][r]);
      }
}

extern "C" void kernel_launch(void* const* d_in, const int* in_sizes, int n_in,
                              void* d_out, int out_size, void* d_ws, size_t ws_size,
                              hipStream_t stream) {
  const float* v = (const float*)d_in[0];
  const float* k = (const float*)d_in[1];
  const float* q = (const float*)d_in[2];
  const int* mask = (const int*)d_in[3];
  const int* diff = (const int*)d_in[4];
  const float* relbias = (const float*)d_in[5];
  float* out = (float*)d_out;

  _Float16* KF = (_Float16*)d_ws;
  _Float16* VF = KF + KF_HALVES;
  unsigned char* PB = (unsigned char*)(VF + VF_HALVES);
  if (ws_size < (size_t)25165824) return;

  (void)hipMemsetAsync(d_out, 0, (size_t)out_size * sizeof(float), stream);
  pa_prep<<<7168, 256, 0, stream>>>(v, k, diff, mask, KF, VF, PB);
  pa_main<<<1024, 256, 0, stream>>>(KF, VF, PB, q, relbias, out);
}

// Round 11
// 109.500 us; speedup vs baseline: 1.0019x; 1.0019x over previous
//
#include <hip/hip_runtime.h>
#include <hip/hip_fp16.h>
#include <cstdint>
#include <cstddef>

// ---- problem constants ----
#define SEQ 2048
#define DM 1024
#define NH 16
#define NB 20

typedef _Float16 half8 __attribute__((ext_vector_type(8)));
typedef _Float16 half4 __attribute__((ext_vector_type(4)));
typedef _Float16 h2v __attribute__((ext_vector_type(2)));
typedef float f32x4 __attribute__((ext_vector_type(4)));
typedef int i32x4 __attribute__((ext_vector_type(4)));
typedef unsigned int u32;
typedef unsigned int u32x2 __attribute__((ext_vector_type(2)));

// ws layout (25,165,824 B total):
//  KF [2][16][64][2048] halves : per (b,h,kt): [k2][dh][lane][8]       (QK^T A-frags, 16x16x32)
//  VF [2][16][64][2048] halves : per (b,h,kt): [dt][lane][k2*4+r]      (PV B-frags, 16x16x32,
//                                V row k stored at pi-position p=((k>>2)&3)*8+(k>>4)*4+(k&3))
//  PB [2][64][65536] bytes     : per (b,qblk32): [kt][lane][qs][k2][4] bucket*4|sentinel80
#define KF_HALVES 4194304
#define VF_HALVES 4194304

// =================== prepass ===================
__global__ __launch_bounds__(256) void pa_prep(
    const float* __restrict__ v, const float* __restrict__ k,
    const int* __restrict__ diff, const int* __restrict__ mask,
    _Float16* __restrict__ KF, _Float16* __restrict__ VF,
    unsigned char* __restrict__ PB) {
  const int bid = blockIdx.x, tid = threadIdx.x;
  if (bid < 2048) {
    int img = bid >> 4;                    // 0..127 = b*64+kt
    int bb = img >> 6, kt = img & 63;
    int tix = ((bid & 15) << 8) | tid;     // 0..4095
    int r = tix >> 7;                      // row in tile 0..31 (= k2*16+l16)
    int c0 = (tix & 127) << 3;             // col 0..1016
    const float* src = k + ((size_t)(bb * SEQ + kt * 32 + r)) * DM + c0;
    f32x4 a = *(const f32x4*)src;
    f32x4 c = *(const f32x4*)(src + 4);
    half8 o = {(_Float16)a[0], (_Float16)a[1], (_Float16)a[2], (_Float16)a[3],
               (_Float16)c[0], (_Float16)c[1], (_Float16)c[2], (_Float16)c[3]};
    int h = c0 >> 6, dh = (c0 >> 5) & 1, g4 = (c0 >> 3) & 3;
    int k2 = r >> 4, l16 = r & 15;
    int lane = g4 * 16 + l16;
    size_t off = ((size_t)((bb * 16 + h) * 64 + kt)) * 2048 + (k2 * 2 + dh) * 512 + lane * 8;
    *(half8*)(KF + off) = o;
  } else if (bid < 3072) {
    // V fragment tiler for K=32 PV: row k of tile -> frag position p with
    // p such that lane (g4*16+l16) reg j holds V[pi][d=dt*16+l16], pi = j<4 ? g4*4+j : 16+g4*4+j-4
    int b3 = bid - 2048;
    int img = b3 >> 3;                     // 0..127
    int bb = img >> 6, kt = img & 63;
    int tix = ((b3 & 7) << 8) | tid;       // 0..2047
    int kq = tix >> 8;                     // 0..7
    int k2 = kq >> 2, g4 = kq & 3;
    int d0 = (tix & 255) << 2;             // 0..1020
    const float* src = v + ((size_t)(bb * SEQ + kt * 32 + k2 * 16 + g4 * 4)) * DM + d0;
    f32x4 m0 = *(const f32x4*)(src);
    f32x4 m1 = *(const f32x4*)(src + DM);
    f32x4 m2 = *(const f32x4*)(src + 2 * DM);
    f32x4 m3 = *(const f32x4*)(src + 3 * DM);
#pragma unroll
    for (int i = 0; i < 4; ++i) {
      int d = d0 + i;
      int l16 = d & 15, dt = (d >> 4) & 3, h = d >> 6;
      int lane = g4 * 16 + l16;
      half4 o = {(_Float16)m0[i], (_Float16)m1[i], (_Float16)m2[i], (_Float16)m3[i]};
      // rows k2*16+g4*4+0..3 land at lane regs k2*4+0..3 of frag dt
      size_t off = ((size_t)((bb * 16 + h) * 64 + kt)) * 2048 + dt * 512 + lane * 8 + k2 * 4;
      *(half4*)(VF + off) = o;
    }
  } else {
    int b4 = bid - 3072;                   // 0..4095
    int job = b4 >> 5;                     // 0..127 = b*64+qblk
    int bb = job >> 6, qblk = job & 63;
    int tix = ((b4 & 31) << 8) | tid;      // 0..8191
    int kt = tix >> 7;
    int rem = tix & 127;
    int g4 = rem & 3, l16 = (rem >> 2) & 15, qs = rem >> 6;
    int lane = g4 * 16 + l16;
    int qrow = qblk * 32 + qs * 16 + l16;
    size_t rowbase = ((size_t)(bb * SEQ + qrow)) * SEQ;
    u32x2 wds;
#pragma unroll
    for (int k2 = 0; k2 < 2; ++k2) {
      int kk = kt * 32 + k2 * 16 + g4 * 4;
      i32x4 dv = *(const i32x4*)(diff + rowbase + kk);
      i32x4 mv = *(const i32x4*)(mask + rowbase + kk);
      u32 wd = 0;
#pragma unroll
      for (int r = 0; r < 4; ++r) {
        u32 byte = mv[r] ? ((u32)dv[r] << 2) : 80u;  // bucket*4; 80 = masked sentinel lane 20
        wd |= byte << (8 * r);
      }
      wds[k2] = wd;
    }
    size_t off = ((size_t)job) * 65536 + (size_t)kt * 1024 + (size_t)lane * 16 + (size_t)qs * 8;
    *(u32x2*)(PB + off) = wds;
  }
}

__device__ __forceinline__ void gll16(const _Float16* g, _Float16* l) {
  __builtin_amdgcn_global_load_lds(
      (const __attribute__((address_space(1))) unsigned int*)g,
      (__attribute__((address_space(3))) unsigned int*)l, 16, 0, 0);
}

// packed-f16 silu; bias already in s (came through the MFMA C-operand in f32)
__device__ __forceinline__ half4 silu4nb(const f32x4& s) {
  h2v x01 = __builtin_bit_cast(h2v, __builtin_amdgcn_cvt_pkrtz(s[0], s[1]));
  h2v x23 = __builtin_bit_cast(h2v, __builtin_amdgcn_cvt_pkrtz(s[2], s[3]));
  const h2v NL2E = {(_Float16)-1.44269504f, (_Float16)-1.44269504f};
  const h2v ONE = {(_Float16)1.0f, (_Float16)1.0f};
  h2v m01 = x01 * NL2E, m23 = x23 * NL2E;
  h2v e01 = __builtin_bit_cast(h2v, h2exp2(__builtin_bit_cast(__half2, m01)));
  h2v e23 = __builtin_bit_cast(h2v, h2exp2(__builtin_bit_cast(__half2, m23)));
  h2v d01 = e01 + ONE, d23 = e23 + ONE;
  h2v y01 = x01 * __builtin_bit_cast(h2v, h2rcp(__builtin_bit_cast(__half2, d01)));
  h2v y23 = x23 * __builtin_bit_cast(h2v, h2rcp(__builtin_bit_cast(__half2, d23)));
  return (half4){y01[0], y01[1], y23[0], y23[1]};
}

struct BiasSet { f32x4 b[2][2]; };  // [qs][k2], f32 — feeds QK C-operand

__device__ __forceinline__ void gather_bias(BiasSet& bs, const i32x4& pq, int rbi) {
#pragma unroll
  for (int qs = 0; qs < 2; ++qs)
#pragma unroll
    for (int k2 = 0; k2 < 2; ++k2) {
      u32 u = (u32)pq[qs * 2 + k2];
      bs.b[qs][k2][0] = __int_as_float(__builtin_amdgcn_ds_bpermute((int)(u & 0xffu), rbi));
      bs.b[qs][k2][1] = __int_as_float(__builtin_amdgcn_ds_bpermute((int)((u >> 8) & 0xffu), rbi));
      bs.b[qs][k2][2] = __int_as_float(__builtin_amdgcn_ds_bpermute((int)((u >> 16) & 0xffu), rbi));
      bs.b[qs][k2][3] = __int_as_float(__builtin_amdgcn_ds_bpermute((int)(u >> 24), rbi));
    }
}

// =================== main: instruction-diet (K=32 PV + bias-in-C) ===================
// All pipes <30% across 6 structures -> latency-bound at ~2.6 waves/SIMD; time scales with
// per-tile instruction stream. Diet: PV 16->8 MFMAs via pi-reordered V (K=32), bias into
// QK C-operand (f32, gathered one tile early per R9 — not in-tile like R8's failure).
__global__ __launch_bounds__(256, 4) void pa_main(
    const _Float16* __restrict__ KF, const _Float16* __restrict__ VF,
    const unsigned char* __restrict__ PB, const float* __restrict__ q,
    const float* __restrict__ relbias, float* __restrict__ out) {
  __shared__ _Float16 ldsK[2][2048];
  __shared__ _Float16 ldsV[2][2048];

  const int tid = threadIdx.x, lane = tid & 63, wid = tid >> 6;
  const int l16 = lane & 15, g4 = lane >> 4;
  const int L = (blockIdx.x & 7) * 128 + (blockIdx.x >> 3);   // bijective, 8 XCDs x 128
  const int h = L & 15;
  const int qgrp = (L >> 4) & 15;
  const int ksp = (L >> 8) & 1;
  const int b = L >> 9;
  const int qblk = qgrp * 4 + wid;
  const int qbase = qblk * 32;

  const float rbv = (lane < NB) ? relbias[lane * NH + h] : -30000.0f;
  const int rbi = __float_as_int(rbv);

  half8 qf[2][2];
#pragma unroll
  for (int qs = 0; qs < 2; ++qs)
#pragma unroll
    for (int dh = 0; dh < 2; ++dh) {
      const float* s = q + ((size_t)(b * SEQ + qbase + qs * 16 + l16)) * DM + h * 64 + dh * 32 + g4 * 8;
      f32x4 a = *(const f32x4*)s;
      f32x4 c = *(const f32x4*)(s + 4);
      qf[qs][dh] = {(_Float16)(a[0] * 0.125f), (_Float16)(a[1] * 0.125f),
                    (_Float16)(a[2] * 0.125f), (_Float16)(a[3] * 0.125f),
                    (_Float16)(c[0] * 0.125f), (_Float16)(c[1] * 0.125f),
                    (_Float16)(c[2] * 0.125f), (_Float16)(c[3] * 0.125f)};
    }

  f32x4 acc[2][4];
#pragma unroll
  for (int qs = 0; qs < 2; ++qs)
#pragma unroll
    for (int dt = 0; dt < 4; ++dt) acc[qs][dt] = (f32x4){0.f, 0.f, 0.f, 0.f};

  const _Float16* kfb = KF + ((size_t)((b * 16 + h) * 64 + ksp * 32)) * 2048 + lane * 8;
  const _Float16* vfb = VF + ((size_t)((b * 16 + h) * 64 + ksp * 32)) * 2048 + lane * 8;
  const unsigned char* pbb = PB + ((size_t)(b * 64 + qblk)) * 65536 + (size_t)(ksp * 32) * 1024 + lane * 16;
  const int c512 = wid * 512;

#define STAGE(T, B)                                          \
  do {                                                       \
    gll16(kfb + (size_t)(T) * 2048 + c512, &ldsK[B][c512]);  \
    gll16(vfb + (size_t)(T) * 2048 + c512, &ldsV[B][c512]);  \
  } while (0)
#define CLMP(T) ((T) < 32 ? (T) : 31)

#define COMPUTE(B, BS)                                                                       \
  do {                                                                                       \
    half8 kfr[4], vvr[4];                                                                    \
    _Pragma("unroll") for (int j = 0; j < 4; ++j) {                                          \
      kfr[j] = *(const half8*)&ldsK[B][j * 512 + lane * 8];                                  \
      vvr[j] = *(const half8*)&ldsV[B][j * 512 + lane * 8];                                  \
    }                                                                                        \
    f32x4 sa[2][2];                                                                          \
    _Pragma("unroll") for (int qs = 0; qs < 2; ++qs)                                         \
      _Pragma("unroll") for (int k2 = 0; k2 < 2; ++k2) {                                     \
        sa[qs][k2] = __builtin_amdgcn_mfma_f32_16x16x32_f16(kfr[k2 * 2 + 0], qf[qs][0],      \
                                                            BS.b[qs][k2], 0, 0, 0);          \
        sa[qs][k2] = __builtin_amdgcn_mfma_f32_16x16x32_f16(kfr[k2 * 2 + 1], qf[qs][1],      \
                                                            sa[qs][k2], 0, 0, 0);            \
      }                                                                                      \
    half8 pf8[2];                                                                            \
    _Pragma("unroll") for (int qs = 0; qs < 2; ++qs) {                                       \
      half4 p0 = silu4nb(sa[qs][0]);                                                         \
      half4 p1 = silu4nb(sa[qs][1]);                                                         \
      pf8[qs] = (half8){p0[0], p0[1], p0[2], p0[3], p1[0], p1[1], p1[2], p1[3]};             \
    }                                                                                        \
    _Pragma("unroll") for (int qs = 0; qs < 2; ++qs)                                         \
      _Pragma("unroll") for (int dt = 0; dt < 4; ++dt)                                       \
        acc[qs][dt] = __builtin_amdgcn_mfma_f32_16x16x32_f16(pf8[qs], vvr[dt],               \
                                                             acc[qs][dt], 0, 0, 0);          \
  } while (0)

  BiasSet biasA, biasB;
  i32x4 pq1, pqX;

  // prologue: stage tile0 -> buf0; bias(0); pq(1) in flight
  STAGE(0, 0);
  i32x4 pq0 = *(const i32x4*)(pbb);
  pq1 = *(const i32x4*)(pbb + 1024);
  __syncthreads();                      // drains stage(0)
  gather_bias(biasA, pq0, rbi);

  for (int t = 0; t < 32; t += 2) {
    // even phase: stage t+1 -> buf1; compute t from buf0
    STAGE(t + 1, 1);
    pqX = *(const i32x4*)(pbb + (size_t)CLMP(t + 2) * 1024);
    __builtin_amdgcn_sched_barrier(0);
    gather_bias(biasB, pq1, rbi);       // bias for t+1, hides under compute t
    COMPUTE(0, biasA);
    __syncthreads();                    // buf1 ready; all waves done with buf0
    // odd phase: stage t+2 -> buf0; compute t+1 from buf1
    STAGE(CLMP(t + 2), 0);
    pq1 = *(const i32x4*)(pbb + (size_t)CLMP(t + 3) * 1024);
    __builtin_amdgcn_sched_barrier(0);
    gather_bias(biasA, pqX, rbi);       // bias for t+2
    COMPUTE(1, biasB);
    __syncthreads();
  }
#undef STAGE
#undef CLMP
#undef COMPUTE

  // epilogue: ksplit=2 partials -> atomicAdd into zeroed out
#pragma unroll
  for (int qs = 0; qs < 2; ++qs)
#pragma unroll
    for (int dt = 0; dt < 4; ++dt)
#pragma unroll
      for (int r = 0; r < 4; ++r) {
        int qrow = qbase + qs * 16 + g4 * 4 + r;
        int d = h * 64 + dt * 16 + l16;
        atomicAdd(&out[((size_t)(b * SEQ) + qrow) * DM + d], acc[qs][dt][r]);
      }
}

extern "C" void kernel_launch(void* const* d_in, const int* in_sizes, int n_in,
                              void* d_out, int out_size, void* d_ws, size_t ws_size,
                              hipStream_t stream) {
  const float* v = (const float*)d_in[0];
  const float* k = (const float*)d_in[1];
  const float* q = (const float*)d_in[2];
  const int* mask = (const int*)d_in[3];
  const int* diff = (const int*)d_in[4];
  const float* relbias = (const float*)d_in[5];
  float* out = (float*)d_out;

  _Float16* KF = (_Float16*)d_ws;
  _Float16* VF = KF + KF_HALVES;
  unsigned char* PB = (unsigned char*)(VF + VF_HALVES);
  if (ws_size < (size_t)25165824) return;

  (void)hipMemsetAsync(d_out, 0, (size_t)out_size * sizeof(float), stream);
  pa_prep<<<7168, 256, 0, stream>>>(v, k, diff, mask, KF, VF, PB);
  pa_main<<<1024, 256, 0, stream>>>(KF, VF, PB, q, relbias, out);
}

// Round 12
// 108.585 us; speedup vs baseline: 1.0104x; 1.0084x over previous
//
#include <hip/hip_runtime.h>
#include <hip/hip_fp16.h>
#include <cstdint>
#include <cstddef>

// ---- problem constants ----
#define SEQ 2048
#define DM 1024
#define NH 16
#define NB 20

typedef _Float16 half8 __attribute__((ext_vector_type(8)));
typedef _Float16 half4 __attribute__((ext_vector_type(4)));
typedef _Float16 h2v __attribute__((ext_vector_type(2)));
typedef float f32x4 __attribute__((ext_vector_type(4)));
typedef int i32x4 __attribute__((ext_vector_type(4)));
typedef unsigned int u32;
typedef unsigned int u32x2 __attribute__((ext_vector_type(2)));

// ws layout (25,165,824 B total):
//  KF [2][16][64][2048] halves : per (b,h,kt): [k2][dh][lane][8]       (QK^T A-frags, 16x16x32)
//  VF [2][16][64][2048] halves : per (b,h,kt): [dt][lane][k2*4+r]      (PV B-frags, K=32 pi-order)
//  PB [2][64][65536] bytes     : per (b,qblk32): [kt][lane][qs][k2][4] bucket*4|sentinel80
#define KF_HALVES 4194304
#define VF_HALVES 4194304

// =================== prepass (unchanged from R11) ===================
__global__ __launch_bounds__(256) void pa_prep(
    const float* __restrict__ v, const float* __restrict__ k,
    const int* __restrict__ diff, const int* __restrict__ mask,
    _Float16* __restrict__ KF, _Float16* __restrict__ VF,
    unsigned char* __restrict__ PB) {
  const int bid = blockIdx.x, tid = threadIdx.x;
  if (bid < 2048) {
    int img = bid >> 4;                    // 0..127 = b*64+kt
    int bb = img >> 6, kt = img & 63;
    int tix = ((bid & 15) << 8) | tid;     // 0..4095
    int r = tix >> 7;                      // row in tile 0..31 (= k2*16+l16)
    int c0 = (tix & 127) << 3;             // col 0..1016
    const float* src = k + ((size_t)(bb * SEQ + kt * 32 + r)) * DM + c0;
    f32x4 a = *(const f32x4*)src;
    f32x4 c = *(const f32x4*)(src + 4);
    half8 o = {(_Float16)a[0], (_Float16)a[1], (_Float16)a[2], (_Float16)a[3],
               (_Float16)c[0], (_Float16)c[1], (_Float16)c[2], (_Float16)c[3]};
    int h = c0 >> 6, dh = (c0 >> 5) & 1, g4 = (c0 >> 3) & 3;
    int k2 = r >> 4, l16 = r & 15;
    int lane = g4 * 16 + l16;
    size_t off = ((size_t)((bb * 16 + h) * 64 + kt)) * 2048 + (k2 * 2 + dh) * 512 + lane * 8;
    *(half8*)(KF + off) = o;
  } else if (bid < 3072) {
    int b3 = bid - 2048;
    int img = b3 >> 3;                     // 0..127
    int bb = img >> 6, kt = img & 63;
    int tix = ((b3 & 7) << 8) | tid;       // 0..2047
    int kq = tix >> 8;                     // 0..7
    int k2 = kq >> 2, g4 = kq & 3;
    int d0 = (tix & 255) << 2;             // 0..1020
    const float* src = v + ((size_t)(bb * SEQ + kt * 32 + k2 * 16 + g4 * 4)) * DM + d0;
    f32x4 m0 = *(const f32x4*)(src);
    f32x4 m1 = *(const f32x4*)(src + DM);
    f32x4 m2 = *(const f32x4*)(src + 2 * DM);
    f32x4 m3 = *(const f32x4*)(src + 3 * DM);
#pragma unroll
    for (int i = 0; i < 4; ++i) {
      int d = d0 + i;
      int l16 = d & 15, dt = (d >> 4) & 3, h = d >> 6;
      int lane = g4 * 16 + l16;
      half4 o = {(_Float16)m0[i], (_Float16)m1[i], (_Float16)m2[i], (_Float16)m3[i]};
      size_t off = ((size_t)((bb * 16 + h) * 64 + kt)) * 2048 + dt * 512 + lane * 8 + k2 * 4;
      *(half4*)(VF + off) = o;
    }
  } else {
    int b4 = bid - 3072;                   // 0..4095
    int job = b4 >> 5;                     // 0..127 = b*64+qblk32
    int bb = job >> 6, qblk = job & 63;
    int tix = ((b4 & 31) << 8) | tid;      // 0..8191
    int kt = tix >> 7;
    int rem = tix & 127;
    int g4 = rem & 3, l16 = (rem >> 2) & 15, qs = rem >> 6;
    int lane = g4 * 16 + l16;
    int qrow = qblk * 32 + qs * 16 + l16;
    size_t rowbase = ((size_t)(bb * SEQ + qrow)) * SEQ;
    u32x2 wds;
#pragma unroll
    for (int k2 = 0; k2 < 2; ++k2) {
      int kk = kt * 32 + k2 * 16 + g4 * 4;
      i32x4 dv = *(const i32x4*)(diff + rowbase + kk);
      i32x4 mv = *(const i32x4*)(mask + rowbase + kk);
      u32 wd = 0;
#pragma unroll
      for (int r = 0; r < 4; ++r) {
        u32 byte = mv[r] ? ((u32)dv[r] << 2) : 80u;  // bucket*4; 80 = masked sentinel lane 20
        wd |= byte << (8 * r);
      }
      wds[k2] = wd;
    }
    size_t off = ((size_t)job) * 65536 + (size_t)kt * 1024 + (size_t)lane * 16 + (size_t)qs * 8;
    *(u32x2*)(PB + off) = wds;
  }
}

// packed-f16 silu; bias already in s (via QK MFMA C-operand, f32)
__device__ __forceinline__ half4 silu4nb(const f32x4& s) {
  h2v x01 = __builtin_bit_cast(h2v, __builtin_amdgcn_cvt_pkrtz(s[0], s[1]));
  h2v x23 = __builtin_bit_cast(h2v, __builtin_amdgcn_cvt_pkrtz(s[2], s[3]));
  const h2v NL2E = {(_Float16)-1.44269504f, (_Float16)-1.44269504f};
  const h2v ONE = {(_Float16)1.0f, (_Float16)1.0f};
  h2v m01 = x01 * NL2E, m23 = x23 * NL2E;
  h2v e01 = __builtin_bit_cast(h2v, h2exp2(__builtin_bit_cast(__half2, m01)));
  h2v e23 = __builtin_bit_cast(h2v, h2exp2(__builtin_bit_cast(__half2, m23)));
  h2v d01 = e01 + ONE, d23 = e23 + ONE;
  h2v y01 = x01 * __builtin_bit_cast(h2v, h2rcp(__builtin_bit_cast(__half2, d01)));
  h2v y23 = x23 * __builtin_bit_cast(h2v, h2rcp(__builtin_bit_cast(__half2, d23)));
  return (half4){y01[0], y01[1], y23[0], y23[1]};
}

// =================== main: dual independent k-streams per wave ===================
// 9 structures plateaued at 80-90us with all pipes <50%: per-wave IN-ORDER issue stalls on
// one serial chain. Fix: each wave runs TWO independent tile streams (k-halves, separate
// accs) skewed by half an iteration — each stream's ~300cy compute covers the other's
// load+bpermute latency inside program order. QB=16/wave, no LDS, no barriers, no atomics
// (full-k per wave -> direct stores, no memset).
__global__ __launch_bounds__(256, 3) void pa_main(
    const _Float16* __restrict__ KF, const _Float16* __restrict__ VF,
    const unsigned char* __restrict__ PB, const float* __restrict__ q,
    const float* __restrict__ relbias, float* __restrict__ out) {
  const int tid = threadIdx.x, lane = tid & 63, wid = tid >> 6;
  const int l16 = lane & 15, g4 = lane >> 4;
  const int L = (blockIdx.x & 7) * 128 + (blockIdx.x >> 3);   // bijective, 8 XCDs x 128
  const int qg4 = L & 31;
  const int h = (L >> 5) & 15;       // XCD owns 4 heads of one b: K/V 2MB fits its L2
  const int b = L >> 9;
  const int qblk16 = qg4 * 4 + wid;  // wave's 16 q-rows
  const int qbase = qblk16 * 16;
  const int qb32 = qblk16 >> 1, qs1 = qblk16 & 1;

  const float rbv = (lane < NB) ? relbias[lane * NH + h] : -30000.0f;
  const int rbi = __float_as_int(rbv);

  // Q fragments (1 q-subtile), pre-scaled by 1/8
  half8 qf[2];
#pragma unroll
  for (int dh = 0; dh < 2; ++dh) {
    const float* s = q + ((size_t)(b * SEQ + qbase + l16)) * DM + h * 64 + dh * 32 + g4 * 8;
    f32x4 a = *(const f32x4*)s;
    f32x4 c = *(const f32x4*)(s + 4);
    qf[dh] = {(_Float16)(a[0] * 0.125f), (_Float16)(a[1] * 0.125f),
              (_Float16)(a[2] * 0.125f), (_Float16)(a[3] * 0.125f),
              (_Float16)(c[0] * 0.125f), (_Float16)(c[1] * 0.125f),
              (_Float16)(c[2] * 0.125f), (_Float16)(c[3] * 0.125f)};
  }

  f32x4 acc0[4], acc1[4];
#pragma unroll
  for (int dt = 0; dt < 4; ++dt) {
    acc0[dt] = (f32x4){0.f, 0.f, 0.f, 0.f};
    acc1[dt] = (f32x4){0.f, 0.f, 0.f, 0.f};
  }

  const _Float16* kfb = KF + ((size_t)((b * 16 + h) * 64)) * 2048 + lane * 8;
  const _Float16* vfb = VF + ((size_t)((b * 16 + h) * 64)) * 2048 + lane * 8;
  const unsigned char* pbb = PB + ((size_t)(b * 64 + qb32)) * 65536 + (size_t)lane * 16 + qs1 * 8;

  half8 kf0[4], vv0[4], kf1[4], vv1[4];
  u32x2 pq0, pq1;

#define LOADS(T, KR, VR, PQ)                                           \
  do {                                                                 \
    _Pragma("unroll") for (int j = 0; j < 4; ++j) {                    \
      KR[j] = *(const half8*)(kfb + (size_t)(T) * 2048 + j * 512);     \
      VR[j] = *(const half8*)(vfb + (size_t)(T) * 2048 + j * 512);     \
    }                                                                  \
    PQ = *(const u32x2*)(pbb + (size_t)(T) * 1024);                    \
  } while (0)

#define COMPUTE(KR, VR, PQ, ACC)                                                             \
  do {                                                                                       \
    f32x4 sa[2];                                                                             \
    _Pragma("unroll") for (int k2 = 0; k2 < 2; ++k2) {                                       \
      u32 u = (u32)PQ[k2];                                                                   \
      f32x4 bb;                                                                              \
      bb[0] = __int_as_float(__builtin_amdgcn_ds_bpermute((int)(u & 0xffu), rbi));           \
      bb[1] = __int_as_float(__builtin_amdgcn_ds_bpermute((int)((u >> 8) & 0xffu), rbi));    \
      bb[2] = __int_as_float(__builtin_amdgcn_ds_bpermute((int)((u >> 16) & 0xffu), rbi));   \
      bb[3] = __int_as_float(__builtin_amdgcn_ds_bpermute((int)(u >> 24), rbi));             \
      sa[k2] = __builtin_amdgcn_mfma_f32_16x16x32_f16(KR[k2 * 2 + 0], qf[0], bb, 0, 0, 0);   \
      sa[k2] = __builtin_amdgcn_mfma_f32_16x16x32_f16(KR[k2 * 2 + 1], qf[1], sa[k2], 0, 0, 0); \
    }                                                                                        \
    half4 p0 = silu4nb(sa[0]);                                                               \
    half4 p1 = silu4nb(sa[1]);                                                               \
    half8 pf8 = (half8){p0[0], p0[1], p0[2], p0[3], p1[0], p1[1], p1[2], p1[3]};             \
    _Pragma("unroll") for (int dt = 0; dt < 4; ++dt)                                         \
      ACC[dt] = __builtin_amdgcn_mfma_f32_16x16x32_f16(pf8, VR[dt], ACC[dt], 0, 0, 0);       \
  } while (0)

  // prologue: stream0 tile 0 in flight
  LOADS(0, kf0, vv0, pq0);
  __builtin_amdgcn_sched_barrier(0);

  for (int t = 0; t < 32; ++t) {
    // s1 loads issue; s0 computes (its loads aged one compute-block)
    LOADS(t + 32, kf1, vv1, pq1);
    __builtin_amdgcn_sched_barrier(0);
    COMPUTE(kf0, vv0, pq0, acc0);
    // s0 next loads issue; s1 computes
    int tn = (t + 1 < 32) ? t + 1 : 31;
    LOADS(tn, kf0, vv0, pq0);
    __builtin_amdgcn_sched_barrier(0);
    COMPUTE(kf1, vv1, pq1, acc1);
  }
#undef LOADS
#undef COMPUTE

  // epilogue: direct store (full k-range per wave -> no atomics, no memset)
#pragma unroll
  for (int dt = 0; dt < 4; ++dt) {
    f32x4 sum = acc0[dt] + acc1[dt];
#pragma unroll
    for (int r = 0; r < 4; ++r) {
      int qrow = qbase + g4 * 4 + r;
      int d = h * 64 + dt * 16 + l16;
      out[((size_t)(b * SEQ) + qrow) * DM + d] = sum[r];
    }
  }
}

extern "C" void kernel_launch(void* const* d_in, const int* in_sizes, int n_in,
                              void* d_out, int out_size, void* d_ws, size_t ws_size,
                              hipStream_t stream) {
  const float* v = (const float*)d_in[0];
  const float* k = (const float*)d_in[1];
  const float* q = (const float*)d_in[2];
  const int* mask = (const int*)d_in[3];
  const int* diff = (const int*)d_in[4];
  const float* relbias = (const float*)d_in[5];
  float* out = (float*)d_out;

  _Float16* KF = (_Float16*)d_ws;
  _Float16* VF = KF + KF_HALVES;
  unsigned char* PB = (unsigned char*)(VF + VF_HALVES);
  if (ws_size < (size_t)25165824) return;

  pa_prep<<<7168, 256, 0, stream>>>(v, k, diff, mask, KF, VF, PB);
  pa_main<<<1024, 256, 0, stream>>>(KF, VF, PB, q, relbias, out);
}